// Round 1
// baseline (6619.303 us; speedup 1.0000x reference)
//
#include <hip/hip_runtime.h>
#include <hip/hip_bf16.h>
#include <stdint.h>

// ---------------------------------------------------------------------------
// Seq2seq LSTM (2-layer enc + 2-layer dec, B=32, S=T=128, E=512, H=1024).
// Strategy:
//   1. gather_emb: embedding lookup -> bf16 X (t-major rows: row = t*32+b)
//   2. gemm_xp:    XP = X @ Wih^T + (bih+bhh)  (f32 out, bf16 MFMA inputs)
//   3. rnn_layer:  persistent 128-block kernel; Whh (bf16) resident in LDS,
//                  per-step: stage h -> LDS, MFMA gates, pointwise (f32),
//                  grid barrier (agent-scope atomics, sense-reversing).
// Sequential chain: encL0 -> encL1 -> decL0 -> decL1 (dec init = enc finals).
// ---------------------------------------------------------------------------

typedef __attribute__((ext_vector_type(8))) __bf16 bf16x8;
typedef __attribute__((ext_vector_type(4))) __bf16 bf16x4;
typedef __attribute__((ext_vector_type(4))) float  f32x4;

#define RNN_BLOCKS 128
#define RNN_SMEM   (65536 + 65536 + 4096)   // Whh slice + h tile + gates scratch

__device__ __forceinline__ float sigmoidf_(float x) {
  return 1.f / (1.f + __expf(-x));
}
__device__ __forceinline__ float tanhf_(float x) {
  float e = __expf(-2.f * fabsf(x));
  float t = (1.f - e) / (1.f + e);
  return x < 0.f ? -t : t;
}

// ---------------------------------------------------------------------------
__global__ void init_ws(float* zeros, unsigned* bar) {
  int i = blockIdx.x * 256 + threadIdx.x;
  if (i < 32 * 1024) zeros[i] = 0.f;
  if (i == 0) { bar[0] = 0u; bar[1] = 0u; }
}

// ---------------------------------------------------------------------------
// Embedding gather. Xe row = t*32+b <- enc_emb[src[b][t]];
// Xd row = t*32+b <- dec_emb[t==0 ? BOS : tgt[b][t-1]].
__global__ void gather_emb(const int* __restrict__ src, const int* __restrict__ tgt,
                           const float* __restrict__ ee, const float* __restrict__ de,
                           __bf16* __restrict__ Xe, __bf16* __restrict__ Xd) {
  int row = blockIdx.x & 4095;
  int t = row >> 5, b = row & 31;
  bool isd = blockIdx.x >= 4096;
  int tok = isd ? (t == 0 ? 1 : tgt[b * 128 + t - 1]) : src[b * 128 + t];
  const float* ep = (isd ? de : ee) + (size_t)tok * 512;
  __bf16* op = (isd ? Xd : Xe) + (size_t)row * 512;
  int i = threadIdx.x * 4;
  float4 v = *(const float4*)(ep + i);
  bf16x4 t4;
  t4[0] = (__bf16)v.x; t4[1] = (__bf16)v.y; t4[2] = (__bf16)v.z; t4[3] = (__bf16)v.w;
  *(bf16x4*)(op + i) = t4;
}

// ---------------------------------------------------------------------------
// XP[M=4096, N=4096] = A[M,K](bf16) @ W[N,K]^T(f32->bf16) + bih + bhh  (f32 out)
// 128x128 tile, BK=64, 4 waves (64x64 each), XOR-swizzled LDS.
__global__ __launch_bounds__(256) void gemm_xp(
    const __bf16* __restrict__ A, const float* __restrict__ W,
    const float* __restrict__ bih, const float* __restrict__ bhh,
    float* __restrict__ C, int K) {
  __shared__ char sA[128 * 64 * 2];
  __shared__ char sB[128 * 64 * 2];
  int tid = threadIdx.x;
  int lane = tid & 63, wave = tid >> 6;
  int wm = wave & 1, wn = wave >> 1;
  int bm = blockIdx.x & 31, bn = blockIdx.x >> 5;
  int frow = lane & 15;
  int kj = (lane >> 4) * 16;   // byte offset of this lane's 8-elem k-chunk

  f32x4 acc[4][4] = {};

  for (int k0 = 0; k0 < K; k0 += 64) {
#pragma unroll
    for (int c4 = 0; c4 < 4; ++c4) {   // stage A tile (bf16, swizzled)
      int idx = (c4 * 256 + tid) * 8;
      int r = idx >> 6, kk = idx & 63;
      bf16x8 v = *(const bf16x8*)(A + (size_t)(bm * 128 + r) * K + k0 + kk);
      *(bf16x8*)(sA + ((r * 128 + kk * 2) ^ ((r & 7) << 4))) = v;
    }
#pragma unroll
    for (int c4 = 0; c4 < 4; ++c4) {   // stage B tile (f32 -> bf16, swizzled)
      int idx = (c4 * 256 + tid) * 8;
      int r = idx >> 6, kk = idx & 63;
      const float* wp = W + (size_t)(bn * 128 + r) * K + k0 + kk;
      float4 w0 = *(const float4*)wp;
      float4 w1 = *(const float4*)(wp + 4);
      bf16x8 v;
      v[0] = (__bf16)w0.x; v[1] = (__bf16)w0.y; v[2] = (__bf16)w0.z; v[3] = (__bf16)w0.w;
      v[4] = (__bf16)w1.x; v[5] = (__bf16)w1.y; v[6] = (__bf16)w1.z; v[7] = (__bf16)w1.w;
      *(bf16x8*)(sB + ((r * 128 + kk * 2) ^ ((r & 7) << 4))) = v;
    }
    __syncthreads();
#pragma unroll
    for (int half = 0; half < 2; ++half) {
      int kb = half * 64 + kj;
      bf16x8 af[4], bfr[4];
#pragma unroll
      for (int f = 0; f < 4; ++f) {
        int ar = wm * 64 + f * 16 + frow;
        af[f] = *(const bf16x8*)(sA + (ar * 128 + (kb ^ ((ar & 7) << 4))));
        int br = wn * 64 + f * 16 + frow;
        bfr[f] = *(const bf16x8*)(sB + (br * 128 + (kb ^ ((br & 7) << 4))));
      }
#pragma unroll
      for (int fm = 0; fm < 4; ++fm)
#pragma unroll
        for (int fn = 0; fn < 4; ++fn)
          acc[fm][fn] = __builtin_amdgcn_mfma_f32_16x16x32_bf16(af[fm], bfr[fn],
                                                                acc[fm][fn], 0, 0, 0);
    }
    __syncthreads();
  }
  int cm = bm * 128 + wm * 64, cn = bn * 128 + wn * 64;
#pragma unroll
  for (int fn = 0; fn < 4; ++fn) {
    int col = cn + fn * 16 + frow;
    float bias = bih[col] + bhh[col];
#pragma unroll
    for (int fm = 0; fm < 4; ++fm) {
      int r0 = cm + fm * 16 + ((lane >> 4) << 2);
#pragma unroll
      for (int j = 0; j < 4; ++j)
        C[(size_t)(r0 + j) * 4096 + col] = acc[fm][fn][j] + bias;
    }
  }
}

// ---------------------------------------------------------------------------
// Sense-reversing grid barrier, agent scope (cross-XCD safe).
__device__ __forceinline__ void gbar(unsigned* cnt, unsigned* gen, unsigned nb) {
  __syncthreads();
  if (threadIdx.x == 0) {
    unsigned g = __hip_atomic_load(gen, __ATOMIC_ACQUIRE, __HIP_MEMORY_SCOPE_AGENT);
    unsigned a = __hip_atomic_fetch_add(cnt, 1u, __ATOMIC_ACQ_REL, __HIP_MEMORY_SCOPE_AGENT);
    if (a == nb - 1u) {
      __hip_atomic_store(cnt, 0u, __ATOMIC_RELAXED, __HIP_MEMORY_SCOPE_AGENT);
      __hip_atomic_fetch_add(gen, 1u, __ATOMIC_RELEASE, __HIP_MEMORY_SCOPE_AGENT);
    } else {
      while (__hip_atomic_load(gen, __ATOMIC_ACQUIRE, __HIP_MEMORY_SCOPE_AGENT) == g)
        __builtin_amdgcn_s_sleep(1);
    }
  }
  __syncthreads();
}

// ---------------------------------------------------------------------------
// One LSTM layer recurrence, persistent across all 128 steps.
// Grid = 128 blocks x 256 threads (1 block/CU, co-resident).
// Block owns H-cols [blk*8, blk*8+8) -> 32 gate rows (i8,f8 | g8,o8).
// LDS: sW [32][1024] bf16 (swizzled, staged once), sH [32][1024] bf16
// (h_{t-1}, staged per step), sG [32][32] f32 gate scratch.
// Wave w: Mtile = w&1 (b rows), Ntile = w>>1 (gate cols). K=1024 -> 32 MFMAs.
__global__ __launch_bounds__(256) void rnn_layer(
    const float* __restrict__ Whh,   // [4096, 1024] f32
    const float* __restrict__ XP,    // [128*32, 4096] f32 (x-part + biases)
    const __bf16* __restrict__ h0,   // [32, 1024] initial h
    const float* __restrict__ c0,    // [32, 1024] initial c
    __bf16* __restrict__ hseq,       // [128*32, 1024] h outputs (t-major)
    float* __restrict__ cfin,        // [32, 1024] final c
    float* __restrict__ yout,        // nullptr or [B=32,T=128,H=1024] f32
    unsigned* __restrict__ bar) {
  extern __shared__ char smem[];
  char* sWc = smem;
  char* sHc = smem + 65536;
  float* sG = (float*)(smem + 131072);

  int tid = threadIdx.x;
  int blk = blockIdx.x;
  int lane = tid & 63, wave = tid >> 6;
  int mt = wave & 1, nt = wave >> 1;
  int frow = lane & 15;
  int kj = (lane >> 4) * 16;

  // ---- stage Whh slice once: 4 strips (i,f,g,o) of 8 contiguous rows each
  for (int g = 0; g < 4; ++g) {
    const float* sp = Whh + (size_t)(g * 1024 + blk * 8) * 1024;
#pragma unroll
    for (int it = 0; it < 8; ++it) {
      int e = (it * 256 + tid) * 4;
      int rl = e >> 10, k = e & 1023;
      float4 v = *(const float4*)(sp + e);
      bf16x4 t4;
      t4[0] = (__bf16)v.x; t4[1] = (__bf16)v.y; t4[2] = (__bf16)v.z; t4[3] = (__bf16)v.w;
      int r = g * 8 + rl;
      *(bf16x4*)(sWc + ((r << 11) + ((k << 1) ^ ((r & 7) << 4)))) = t4;
    }
  }

  // ---- per-thread cell state: thread owns (b = tid>>3, hl = tid&7)
  int hl = tid & 7, b = tid >> 3;
  float c = c0[b * 1024 + blk * 8 + hl];

  int ar = mt * 16 + frow, br = nt * 16 + frow;
  int asw = (ar & 7) << 4, bsw = (br & 7) << 4;
  const char* aRow = sHc + (ar << 11);
  const char* bRow = sWc + (br << 11);

  for (int t = 0; t < 128; ++t) {
    // ---- stage h_{t-1} -> LDS (swizzled)
    const __bf16* hsrc = (t == 0) ? h0 : (hseq + (size_t)(t - 1) * 32 * 1024);
#pragma unroll
    for (int it = 0; it < 16; ++it) {
      int e = (it * 256 + tid) * 8;
      int r = e >> 10, k = e & 1023;
      bf16x8 v = *(const bf16x8*)(hsrc + e);
      *(bf16x8*)(sHc + ((r << 11) + ((k << 1) ^ ((r & 7) << 4)))) = v;
    }
    __syncthreads();

    // ---- gates tile = h @ Whh_slice^T  (K = 1024)
    f32x4 acc = {0.f, 0.f, 0.f, 0.f};
#pragma unroll
    for (int kk = 0; kk < 32; ++kk) {
      int kb = kk * 64 + kj;
      bf16x8 a  = *(const bf16x8*)(aRow + (kb ^ asw));
      bf16x8 bv = *(const bf16x8*)(bRow + (kb ^ bsw));
      acc = __builtin_amdgcn_mfma_f32_16x16x32_bf16(a, bv, acc, 0, 0, 0);
    }

    // ---- dump accumulators to sG (each wave owns a distinct 16x16 quadrant)
    {
      int col = nt * 16 + frow;
      int r0 = mt * 16 + ((lane >> 4) << 2);
      sG[(r0 + 0) * 32 + col] = acc[0];
      sG[(r0 + 1) * 32 + col] = acc[1];
      sG[(r0 + 2) * 32 + col] = acc[2];
      sG[(r0 + 3) * 32 + col] = acc[3];
    }
    __syncthreads();

    // ---- pointwise LSTM cell (f32), one (b, hcol) per thread
    const float* xr = XP + ((size_t)t * 32 + b) * 4096 + blk * 8 + hl;
    float gi = sG[b * 32 + hl]      + xr[0];
    float gf = sG[b * 32 + 8 + hl]  + xr[1024];
    float gg = sG[b * 32 + 16 + hl] + xr[2048];
    float go = sG[b * 32 + 24 + hl] + xr[3072];
    gi = sigmoidf_(gi);
    gf = sigmoidf_(gf);
    go = sigmoidf_(go);
    gg = tanhf_(gg);
    c = gf * c + gi * gg;
    float h = go * tanhf_(c);
    hseq[((size_t)t * 32 + b) * 1024 + blk * 8 + hl] = (__bf16)h;
    if (yout) yout[((size_t)b * 128 + t) * 1024 + blk * 8 + hl] = h;

    // ---- make h_t visible to all blocks before next step
    gbar(bar, bar + 1, RNN_BLOCKS);
  }
  cfin[b * 1024 + blk * 8 + hl] = c;
}

// ---------------------------------------------------------------------------
extern "C" void kernel_launch(void* const* d_in, const int* in_sizes, int n_in,
                              void* d_out, int out_size, void* d_ws, size_t ws_size,
                              hipStream_t stream) {
  (void)in_sizes; (void)n_in; (void)out_size; (void)ws_size;
  const int*   src     = (const int*)d_in[0];
  const int*   tgt     = (const int*)d_in[1];
  const float* enc_emb = (const float*)d_in[2];
  const float* dec_emb = (const float*)d_in[3];
  const float* W[16];
  for (int i = 0; i < 16; ++i) W[i] = (const float*)d_in[4 + i];
  // enc: Wih0=W[0] Whh0=W[1] bih0=W[2] bhh0=W[3]  Wih1=W[4] Whh1=W[5] b=W[6],W[7]
  // dec: Wih0=W[8] Whh0=W[9] b=W[10],W[11]        Wih1=W[12] Whh1=W[13] b=W[14],W[15]

  char* ws = (char*)d_ws;
  size_t off = 0;
  auto alloc = [&](size_t bytes) {
    char* p = ws + off;
    off += (bytes + 255) & ~(size_t)255;
    return p;
  };
  unsigned* bar  = (unsigned*)alloc(256);
  float*    zeros = (float*)alloc((size_t)32 * 1024 * 4);       // h0/c0 zeros
  __bf16*   Xe   = (__bf16*)alloc((size_t)4096 * 512 * 2);
  __bf16*   Xd   = (__bf16*)alloc((size_t)4096 * 512 * 2);
  float*    XP   = (float*)alloc((size_t)4096 * 4096 * 4);      // reused x-part
  __bf16*   hE0  = (__bf16*)alloc((size_t)4096 * 1024 * 2);
  __bf16*   hE1  = (__bf16*)alloc((size_t)4096 * 1024 * 2);
  __bf16*   hD0  = (__bf16*)alloc((size_t)4096 * 1024 * 2);
  __bf16*   hD1  = (__bf16*)alloc((size_t)4096 * 1024 * 2);
  float*    cE0  = (float*)alloc((size_t)32 * 1024 * 4);
  float*    cE1  = (float*)alloc((size_t)32 * 1024 * 4);
  float*    cdum = (float*)alloc((size_t)32 * 1024 * 4);

  hipFuncSetAttribute((const void*)rnn_layer,
                      hipFuncAttributeMaxDynamicSharedMemorySize, RNN_SMEM);

  init_ws<<<128, 256, 0, stream>>>(zeros, bar);
  gather_emb<<<8192, 128, 0, stream>>>(src, tgt, enc_emb, dec_emb, Xe, Xd);

  // encoder L0
  gemm_xp<<<1024, 256, 0, stream>>>(Xe, W[0], W[2], W[3], XP, 512);
  rnn_layer<<<RNN_BLOCKS, 256, RNN_SMEM, stream>>>(
      W[1], XP, (const __bf16*)zeros, zeros, hE0, cE0, nullptr, bar);
  // encoder L1
  gemm_xp<<<1024, 256, 0, stream>>>(hE0, W[4], W[6], W[7], XP, 1024);
  rnn_layer<<<RNN_BLOCKS, 256, RNN_SMEM, stream>>>(
      W[5], XP, (const __bf16*)zeros, zeros, hE1, cE1, nullptr, bar);
  // decoder L0 (init = enc L0 finals)
  gemm_xp<<<1024, 256, 0, stream>>>(Xd, W[8], W[10], W[11], XP, 512);
  rnn_layer<<<RNN_BLOCKS, 256, RNN_SMEM, stream>>>(
      W[9], XP, hE0 + (size_t)127 * 32 * 1024, cE0, hD0, cdum, nullptr, bar);
  // decoder L1 (init = enc L1 finals) -> writes d_out f32 [B,T,H]
  gemm_xp<<<1024, 256, 0, stream>>>(hD0, W[12], W[14], W[15], XP, 1024);
  rnn_layer<<<RNN_BLOCKS, 256, RNN_SMEM, stream>>>(
      W[13], XP, hE1 + (size_t)127 * 32 * 1024, cE1, hD1, cdum, (float*)d_out, bar);
}

// Round 2
// 6109.449 us; speedup vs baseline: 1.0835x; 1.0835x over previous
//
#include <hip/hip_runtime.h>
#include <hip/hip_bf16.h>
#include <stdint.h>

// ---------------------------------------------------------------------------
// Seq2seq LSTM (2-layer enc + 2-layer dec, B=32, S=T=128, E=512, H=1024).
//   1. gather_emb: embedding lookup -> bf16 X (t-major rows: row = t*32+b)
//   2. gemm_xp:    XP = X @ Wih^T + (bih+bhh)  (f32 out, bf16 MFMA inputs)
//   3. rnn_layer:  persistent 128-block kernel; Whh (bf16) resident in LDS.
//      Per step: poll per-producer flags (parallel, one flag per thread-pair,
//      staging that producer's columns immediately) -> MFMA gates -> pointwise
//      -> write h_t -> release-store own flag. No atomic-counter barrier.
// Sequential chain: encL0 -> encL1 -> decL0 -> decL1 (dec init = enc finals).
// ---------------------------------------------------------------------------

typedef __attribute__((ext_vector_type(8))) __bf16 bf16x8;
typedef __attribute__((ext_vector_type(4))) __bf16 bf16x4;
typedef __attribute__((ext_vector_type(4))) float  f32x4;

#define RNN_BLOCKS 128
#define RNN_SMEM   (65536 + 65536 + 4096)   // Whh slice + h tile + gates scratch

__device__ __forceinline__ float sigmoidf_(float x) {
  return 1.f / (1.f + __expf(-x));
}
__device__ __forceinline__ float tanhf_(float x) {
  float e = __expf(-2.f * fabsf(x));
  float t = (1.f - e) / (1.f + e);
  return x < 0.f ? -t : t;
}

// ---------------------------------------------------------------------------
__global__ void init_ws(float* zeros, unsigned* flags) {
  int i = blockIdx.x * 256 + threadIdx.x;
  if (i < 32 * 1024) zeros[i] = 0.f;
  if (i < 512) flags[i] = 0u;          // 4 layers x 128 producer flags
}

// ---------------------------------------------------------------------------
// Embedding gather. Xe row = t*32+b <- enc_emb[src[b][t]];
// Xd row = t*32+b <- dec_emb[t==0 ? BOS : tgt[b][t-1]].
__global__ void gather_emb(const int* __restrict__ src, const int* __restrict__ tgt,
                           const float* __restrict__ ee, const float* __restrict__ de,
                           __bf16* __restrict__ Xe, __bf16* __restrict__ Xd) {
  int row = blockIdx.x & 4095;
  int t = row >> 5, b = row & 31;
  bool isd = blockIdx.x >= 4096;
  int tok = isd ? (t == 0 ? 1 : tgt[b * 128 + t - 1]) : src[b * 128 + t];
  const float* ep = (isd ? de : ee) + (size_t)tok * 512;
  __bf16* op = (isd ? Xd : Xe) + (size_t)row * 512;
  int i = threadIdx.x * 4;
  float4 v = *(const float4*)(ep + i);
  bf16x4 t4;
  t4[0] = (__bf16)v.x; t4[1] = (__bf16)v.y; t4[2] = (__bf16)v.z; t4[3] = (__bf16)v.w;
  *(bf16x4*)(op + i) = t4;
}

// ---------------------------------------------------------------------------
// XP[M=4096, N=4096] = A[M,K](bf16) @ W[N,K]^T(f32->bf16) + bih + bhh  (f32 out)
// 128x128 tile, BK=64, 4 waves (64x64 each), XOR-swizzled LDS.
__global__ __launch_bounds__(256) void gemm_xp(
    const __bf16* __restrict__ A, const float* __restrict__ W,
    const float* __restrict__ bih, const float* __restrict__ bhh,
    float* __restrict__ C, int K) {
  __shared__ char sA[128 * 64 * 2];
  __shared__ char sB[128 * 64 * 2];
  int tid = threadIdx.x;
  int lane = tid & 63, wave = tid >> 6;
  int wm = wave & 1, wn = wave >> 1;
  int bm = blockIdx.x & 31, bn = blockIdx.x >> 5;
  int frow = lane & 15;
  int kj = (lane >> 4) * 16;   // byte offset of this lane's 8-elem k-chunk

  f32x4 acc[4][4] = {};

  for (int k0 = 0; k0 < K; k0 += 64) {
#pragma unroll
    for (int c4 = 0; c4 < 4; ++c4) {   // stage A tile (bf16, swizzled)
      int idx = (c4 * 256 + tid) * 8;
      int r = idx >> 6, kk = idx & 63;
      bf16x8 v = *(const bf16x8*)(A + (size_t)(bm * 128 + r) * K + k0 + kk);
      *(bf16x8*)(sA + ((r * 128 + kk * 2) ^ ((r & 7) << 4))) = v;
    }
#pragma unroll
    for (int c4 = 0; c4 < 4; ++c4) {   // stage B tile (f32 -> bf16, swizzled)
      int idx = (c4 * 256 + tid) * 8;
      int r = idx >> 6, kk = idx & 63;
      const float* wp = W + (size_t)(bn * 128 + r) * K + k0 + kk;
      float4 w0 = *(const float4*)wp;
      float4 w1 = *(const float4*)(wp + 4);
      bf16x8 v;
      v[0] = (__bf16)w0.x; v[1] = (__bf16)w0.y; v[2] = (__bf16)w0.z; v[3] = (__bf16)w0.w;
      v[4] = (__bf16)w1.x; v[5] = (__bf16)w1.y; v[6] = (__bf16)w1.z; v[7] = (__bf16)w1.w;
      *(bf16x8*)(sB + ((r * 128 + kk * 2) ^ ((r & 7) << 4))) = v;
    }
    __syncthreads();
#pragma unroll
    for (int half = 0; half < 2; ++half) {
      int kb = half * 64 + kj;
      bf16x8 af[4], bfr[4];
#pragma unroll
      for (int f = 0; f < 4; ++f) {
        int ar = wm * 64 + f * 16 + frow;
        af[f] = *(const bf16x8*)(sA + (ar * 128 + (kb ^ ((ar & 7) << 4))));
        int br = wn * 64 + f * 16 + frow;
        bfr[f] = *(const bf16x8*)(sB + (br * 128 + (kb ^ ((br & 7) << 4))));
      }
#pragma unroll
      for (int fm = 0; fm < 4; ++fm)
#pragma unroll
        for (int fn = 0; fn < 4; ++fn)
          acc[fm][fn] = __builtin_amdgcn_mfma_f32_16x16x32_bf16(af[fm], bfr[fn],
                                                                acc[fm][fn], 0, 0, 0);
    }
    __syncthreads();
  }
  int cm = bm * 128 + wm * 64, cn = bn * 128 + wn * 64;
#pragma unroll
  for (int fn = 0; fn < 4; ++fn) {
    int col = cn + fn * 16 + frow;
    float bias = bih[col] + bhh[col];
#pragma unroll
    for (int fm = 0; fm < 4; ++fm) {
      int r0 = cm + fm * 16 + ((lane >> 4) << 2);
#pragma unroll
      for (int j = 0; j < 4; ++j)
        C[(size_t)(r0 + j) * 4096 + col] = acc[fm][fn][j] + bias;
    }
  }
}

// ---------------------------------------------------------------------------
// One LSTM layer recurrence, persistent across all 128 steps.
// Grid = 128 blocks x 256 threads (1 block/CU, all co-resident).
// Block owns H-cols [blk*8, blk*8+8) -> 32 gate rows (i8,f8 | g8,o8).
// Sync: flags[j] = number of steps producer j has published. Thread pair
// (2t, 2t+1) polls flags[tid>>1] then stages that producer's 8 columns
// (16 rows each) into LDS -- broadcast overlaps with waiting.
__global__ __launch_bounds__(256) void rnn_layer(
    const float* __restrict__ Whh,   // [4096, 1024] f32
    const float* __restrict__ XP,    // [128*32, 4096] f32 (x-part + biases)
    const __bf16* __restrict__ h0,   // [32, 1024] initial h
    const float* __restrict__ c0,    // [32, 1024] initial c
    __bf16* __restrict__ hseq,       // [128*32, 1024] h outputs (t-major)
    float* __restrict__ cfin,        // [32, 1024] final c
    float* __restrict__ yout,        // nullptr or [B=32,T=128,H=1024] f32
    unsigned* __restrict__ flags) {  // [128] this layer's produce flags
  extern __shared__ char smem[];
  char* sWc = smem;
  char* sHc = smem + 65536;
  float* sG = (float*)(smem + 131072);

  int tid = threadIdx.x;
  int blk = blockIdx.x;
  int lane = tid & 63, wave = tid >> 6;
  int mt = wave & 1, nt = wave >> 1;
  int frow = lane & 15;
  int kj = (lane >> 4) * 16;

  // ---- stage Whh slice once: 4 strips (i,f,g,o) of 8 contiguous rows each
  for (int g = 0; g < 4; ++g) {
    const float* sp = Whh + (size_t)(g * 1024 + blk * 8) * 1024;
#pragma unroll
    for (int it = 0; it < 8; ++it) {
      int e = (it * 256 + tid) * 4;
      int rl = e >> 10, k = e & 1023;
      float4 v = *(const float4*)(sp + e);
      bf16x4 t4;
      t4[0] = (__bf16)v.x; t4[1] = (__bf16)v.y; t4[2] = (__bf16)v.z; t4[3] = (__bf16)v.w;
      int r = g * 8 + rl;
      *(bf16x4*)(sWc + ((r << 11) + ((k << 1) ^ ((r & 7) << 4)))) = t4;
    }
  }

  // ---- per-thread cell state: thread owns (b = tid>>3, hl = tid&7)
  int hl = tid & 7, b = tid >> 3;
  float c = c0[b * 1024 + blk * 8 + hl];

  int ar = mt * 16 + frow, br = nt * 16 + frow;
  int asw = (ar & 7) << 4, bsw = (br & 7) << 4;
  const char* aRow = sHc + (ar << 11);
  const char* bRow = sWc + (br << 11);

  int jprod = tid >> 1;          // producer block this thread stages from
  int rbase = (tid & 1) * 16;    // which 16 batch rows of it

  for (int t = 0; t < 128; ++t) {
    // ---- prefetch XP operands (independent of flags)
    const float* xr = XP + ((size_t)t * 32 + b) * 4096 + blk * 8 + hl;
    float xi = xr[0], xf = xr[1024], xg = xr[2048], xo = xr[3072];

    // ---- wait for producer jprod, then stage its 8 columns (16 rows)
    const __bf16* hsrc = (t == 0) ? h0 : (hseq + (size_t)(t - 1) * 32 * 1024);
    if (t > 0) {
      while (__hip_atomic_load(flags + jprod, __ATOMIC_RELAXED,
                               __HIP_MEMORY_SCOPE_AGENT) < (unsigned)t) {}
      __builtin_amdgcn_fence(__ATOMIC_ACQUIRE, "agent");
    }
    {
      const __bf16* src = hsrc + jprod * 8;
      int csw = jprod * 16;   // byte col offset of this producer's chunk
#pragma unroll
      for (int r = 0; r < 16; ++r) {
        int row = rbase + r;
        bf16x8 v = *(const bf16x8*)(src + (size_t)row * 1024);
        *(bf16x8*)(sHc + ((row << 11) + (csw ^ ((row & 7) << 4)))) = v;
      }
    }
    __syncthreads();

    // ---- gates tile = h @ Whh_slice^T  (K = 1024)
    f32x4 acc = {0.f, 0.f, 0.f, 0.f};
#pragma unroll
    for (int kk = 0; kk < 32; ++kk) {
      int kb = kk * 64 + kj;
      bf16x8 a  = *(const bf16x8*)(aRow + (kb ^ asw));
      bf16x8 bv = *(const bf16x8*)(bRow + (kb ^ bsw));
      acc = __builtin_amdgcn_mfma_f32_16x16x32_bf16(a, bv, acc, 0, 0, 0);
    }

    // ---- dump accumulators to sG (each wave owns a distinct 16x16 quadrant)
    {
      int col = nt * 16 + frow;
      int r0 = mt * 16 + ((lane >> 4) << 2);
      sG[(r0 + 0) * 32 + col] = acc[0];
      sG[(r0 + 1) * 32 + col] = acc[1];
      sG[(r0 + 2) * 32 + col] = acc[2];
      sG[(r0 + 3) * 32 + col] = acc[3];
    }
    __syncthreads();

    // ---- pointwise LSTM cell (f32), one (b, hcol) per thread
    float gi = sigmoidf_(sG[b * 32 + hl]      + xi);
    float gf = sigmoidf_(sG[b * 32 + 8 + hl]  + xf);
    float go = sigmoidf_(sG[b * 32 + 24 + hl] + xo);
    float gg = tanhf_(sG[b * 32 + 16 + hl]    + xg);
    c = gf * c + gi * gg;
    float h = go * tanhf_(c);
    hseq[((size_t)t * 32 + b) * 1024 + blk * 8 + hl] = (__bf16)h;
    if (yout) yout[((size_t)b * 128 + t) * 1024 + blk * 8 + hl] = h;

    // ---- publish h_t: barrier drains stores (vmcnt0), then release flag
    __syncthreads();
    if (tid == 0)
      __hip_atomic_store(flags + blk, (unsigned)(t + 1), __ATOMIC_RELEASE,
                         __HIP_MEMORY_SCOPE_AGENT);
  }
  cfin[b * 1024 + blk * 8 + hl] = c;
}

// ---------------------------------------------------------------------------
extern "C" void kernel_launch(void* const* d_in, const int* in_sizes, int n_in,
                              void* d_out, int out_size, void* d_ws, size_t ws_size,
                              hipStream_t stream) {
  (void)in_sizes; (void)n_in; (void)out_size; (void)ws_size;
  const int*   src     = (const int*)d_in[0];
  const int*   tgt     = (const int*)d_in[1];
  const float* enc_emb = (const float*)d_in[2];
  const float* dec_emb = (const float*)d_in[3];
  const float* W[16];
  for (int i = 0; i < 16; ++i) W[i] = (const float*)d_in[4 + i];
  // enc: Wih0=W[0] Whh0=W[1] bih0=W[2] bhh0=W[3]  Wih1=W[4] Whh1=W[5] b=W[6],W[7]
  // dec: Wih0=W[8] Whh0=W[9] b=W[10],W[11]        Wih1=W[12] Whh1=W[13] b=W[14],W[15]

  char* ws = (char*)d_ws;
  size_t off = 0;
  auto alloc = [&](size_t bytes) {
    char* p = ws + off;
    off += (bytes + 255) & ~(size_t)255;
    return p;
  };
  unsigned* flags = (unsigned*)alloc(4 * 128 * sizeof(unsigned));
  float*    zeros = (float*)alloc((size_t)32 * 1024 * 4);       // h0/c0 zeros
  __bf16*   Xe   = (__bf16*)alloc((size_t)4096 * 512 * 2);
  __bf16*   Xd   = (__bf16*)alloc((size_t)4096 * 512 * 2);
  float*    XP   = (float*)alloc((size_t)4096 * 4096 * 4);      // reused x-part
  __bf16*   hE0  = (__bf16*)alloc((size_t)4096 * 1024 * 2);
  __bf16*   hE1  = (__bf16*)alloc((size_t)4096 * 1024 * 2);
  __bf16*   hD0  = (__bf16*)alloc((size_t)4096 * 1024 * 2);
  __bf16*   hD1  = (__bf16*)alloc((size_t)4096 * 1024 * 2);
  float*    cE0  = (float*)alloc((size_t)32 * 1024 * 4);
  float*    cE1  = (float*)alloc((size_t)32 * 1024 * 4);
  float*    cdum = (float*)alloc((size_t)32 * 1024 * 4);

  hipFuncSetAttribute((const void*)rnn_layer,
                      hipFuncAttributeMaxDynamicSharedMemorySize, RNN_SMEM);

  init_ws<<<128, 256, 0, stream>>>(zeros, flags);
  gather_emb<<<8192, 128, 0, stream>>>(src, tgt, enc_emb, dec_emb, Xe, Xd);

  // encoder L0
  gemm_xp<<<1024, 256, 0, stream>>>(Xe, W[0], W[2], W[3], XP, 512);
  rnn_layer<<<RNN_BLOCKS, 256, RNN_SMEM, stream>>>(
      W[1], XP, (const __bf16*)zeros, zeros, hE0, cE0, nullptr, flags + 0);
  // encoder L1
  gemm_xp<<<1024, 256, 0, stream>>>(hE0, W[4], W[6], W[7], XP, 1024);
  rnn_layer<<<RNN_BLOCKS, 256, RNN_SMEM, stream>>>(
      W[5], XP, (const __bf16*)zeros, zeros, hE1, cE1, nullptr, flags + 128);
  // decoder L0 (init = enc L0 finals)
  gemm_xp<<<1024, 256, 0, stream>>>(Xd, W[8], W[10], W[11], XP, 512);
  rnn_layer<<<RNN_BLOCKS, 256, RNN_SMEM, stream>>>(
      W[9], XP, hE0 + (size_t)127 * 32 * 1024, cE0, hD0, cdum, nullptr, flags + 256);
  // decoder L1 (init = enc L1 finals) -> writes d_out f32 [B,T,H]
  gemm_xp<<<1024, 256, 0, stream>>>(hD0, W[12], W[14], W[15], XP, 1024);
  rnn_layer<<<RNN_BLOCKS, 256, RNN_SMEM, stream>>>(
      W[13], XP, hE1 + (size_t)127 * 32 * 1024, cE1, hD1, cdum, (float*)d_out, flags + 384);
}

// Round 3
// 5932.286 us; speedup vs baseline: 1.1158x; 1.0299x over previous
//
#include <hip/hip_runtime.h>
#include <hip/hip_bf16.h>
#include <stdint.h>

// ---------------------------------------------------------------------------
// Seq2seq LSTM (2-layer enc + 2-layer dec, B=32, S=T=128, E=512, H=1024).
//   1. gather_emb: embedding lookup -> bf16 X (t-major rows: row = t*32+b)
//   2. gemm_xp:    XP = X @ Wih^T + (bih+bhh)  (f32 out, bf16 MFMA inputs)
//   3. rnn_layer:  persistent 128-block kernel; Whh (bf16) resident in LDS.
//      Fence-free handoff: producers publish h via agent-scope write-through
//      atomic stores (vmcnt-drained before a release flag); consumers poll
//      with a single wave (s_sleep backoff) and read h via agent-scope
//      bypassing atomic loads -> no buffer_inv / buffer_wbl2 on the path.
// Sequential chain: encL0 -> encL1 -> decL0 -> decL1 (dec init = enc finals).
// ---------------------------------------------------------------------------

typedef __attribute__((ext_vector_type(8))) __bf16 bf16x8;
typedef __attribute__((ext_vector_type(4))) __bf16 bf16x4;
typedef __attribute__((ext_vector_type(4))) float  f32x4;
typedef __attribute__((ext_vector_type(2))) unsigned long long u64x2;

#define RNN_BLOCKS 128
// LDS: Whh slice 64KB + h tile 64KB + sG (32x33 f32 = 4224B) + sP (512B)
#define RNN_SMEM   (65536 + 65536 + 6144)

__device__ __forceinline__ float sigmoidf_(float x) {
  return 1.f / (1.f + __expf(-x));
}
__device__ __forceinline__ float tanhf_(float x) {
  float e = __expf(-2.f * fabsf(x));
  float t = (1.f - e) / (1.f + e);
  return x < 0.f ? -t : t;
}

// ---------------------------------------------------------------------------
__global__ void init_ws(float* zeros, unsigned* flags) {
  int i = blockIdx.x * 256 + threadIdx.x;
  if (i < 32 * 1024) zeros[i] = 0.f;
  if (i < 512) flags[i] = 0u;          // 4 layers x 128 producer flags
}

// ---------------------------------------------------------------------------
// Embedding gather. Xe row = t*32+b <- enc_emb[src[b][t]];
// Xd row = t*32+b <- dec_emb[t==0 ? BOS : tgt[b][t-1]].
__global__ void gather_emb(const int* __restrict__ src, const int* __restrict__ tgt,
                           const float* __restrict__ ee, const float* __restrict__ de,
                           __bf16* __restrict__ Xe, __bf16* __restrict__ Xd) {
  int row = blockIdx.x & 4095;
  int t = row >> 5, b = row & 31;
  bool isd = blockIdx.x >= 4096;
  int tok = isd ? (t == 0 ? 1 : tgt[b * 128 + t - 1]) : src[b * 128 + t];
  const float* ep = (isd ? de : ee) + (size_t)tok * 512;
  __bf16* op = (isd ? Xd : Xe) + (size_t)row * 512;
  int i = threadIdx.x * 4;
  float4 v = *(const float4*)(ep + i);
  bf16x4 t4;
  t4[0] = (__bf16)v.x; t4[1] = (__bf16)v.y; t4[2] = (__bf16)v.z; t4[3] = (__bf16)v.w;
  *(bf16x4*)(op + i) = t4;
}

// ---------------------------------------------------------------------------
// XP[M=4096, N=4096] = A[M,K](bf16) @ W[N,K]^T(f32->bf16) + bih + bhh  (f32 out)
// 128x128 tile, BK=64, 4 waves (64x64 each), XOR-swizzled LDS.
__global__ __launch_bounds__(256) void gemm_xp(
    const __bf16* __restrict__ A, const float* __restrict__ W,
    const float* __restrict__ bih, const float* __restrict__ bhh,
    float* __restrict__ C, int K) {
  __shared__ char sA[128 * 64 * 2];
  __shared__ char sB[128 * 64 * 2];
  int tid = threadIdx.x;
  int lane = tid & 63, wave = tid >> 6;
  int wm = wave & 1, wn = wave >> 1;
  int bm = blockIdx.x & 31, bn = blockIdx.x >> 5;
  int frow = lane & 15;
  int kj = (lane >> 4) * 16;   // byte offset of this lane's 8-elem k-chunk

  f32x4 acc[4][4] = {};

  for (int k0 = 0; k0 < K; k0 += 64) {
#pragma unroll
    for (int c4 = 0; c4 < 4; ++c4) {   // stage A tile (bf16, swizzled)
      int idx = (c4 * 256 + tid) * 8;
      int r = idx >> 6, kk = idx & 63;
      bf16x8 v = *(const bf16x8*)(A + (size_t)(bm * 128 + r) * K + k0 + kk);
      *(bf16x8*)(sA + ((r * 128 + kk * 2) ^ ((r & 7) << 4))) = v;
    }
#pragma unroll
    for (int c4 = 0; c4 < 4; ++c4) {   // stage B tile (f32 -> bf16, swizzled)
      int idx = (c4 * 256 + tid) * 8;
      int r = idx >> 6, kk = idx & 63;
      const float* wp = W + (size_t)(bn * 128 + r) * K + k0 + kk;
      float4 w0 = *(const float4*)wp;
      float4 w1 = *(const float4*)(wp + 4);
      bf16x8 v;
      v[0] = (__bf16)w0.x; v[1] = (__bf16)w0.y; v[2] = (__bf16)w0.z; v[3] = (__bf16)w0.w;
      v[4] = (__bf16)w1.x; v[5] = (__bf16)w1.y; v[6] = (__bf16)w1.z; v[7] = (__bf16)w1.w;
      *(bf16x8*)(sB + ((r * 128 + kk * 2) ^ ((r & 7) << 4))) = v;
    }
    __syncthreads();
#pragma unroll
    for (int half = 0; half < 2; ++half) {
      int kb = half * 64 + kj;
      bf16x8 af[4], bfr[4];
#pragma unroll
      for (int f = 0; f < 4; ++f) {
        int ar = wm * 64 + f * 16 + frow;
        af[f] = *(const bf16x8*)(sA + (ar * 128 + (kb ^ ((ar & 7) << 4))));
        int br = wn * 64 + f * 16 + frow;
        bfr[f] = *(const bf16x8*)(sB + (br * 128 + (kb ^ ((br & 7) << 4))));
      }
#pragma unroll
      for (int fm = 0; fm < 4; ++fm)
#pragma unroll
        for (int fn = 0; fn < 4; ++fn)
          acc[fm][fn] = __builtin_amdgcn_mfma_f32_16x16x32_bf16(af[fm], bfr[fn],
                                                                acc[fm][fn], 0, 0, 0);
    }
    __syncthreads();
  }
  int cm = bm * 128 + wm * 64, cn = bn * 128 + wn * 64;
#pragma unroll
  for (int fn = 0; fn < 4; ++fn) {
    int col = cn + fn * 16 + frow;
    float bias = bih[col] + bhh[col];
#pragma unroll
    for (int fm = 0; fm < 4; ++fm) {
      int r0 = cm + fm * 16 + ((lane >> 4) << 2);
#pragma unroll
      for (int j = 0; j < 4; ++j)
        C[(size_t)(r0 + j) * 4096 + col] = acc[fm][fn][j] + bias;
    }
  }
}

// ---------------------------------------------------------------------------
// One LSTM layer recurrence, persistent across all 128 steps.
// Grid = 128 blocks x 256 threads (1 block/CU, all co-resident).
// Block owns H-cols [blk*8, blk*8+8) -> 32 gate rows (i8,f8 | g8,o8).
// Sync protocol (fence-free):
//   producer: LDS-repack h -> 64 threads do b64 agent-scope write-through
//             stores -> s_waitcnt vmcnt(0) -> __syncthreads -> release flag.
//   consumer: wave 0 polls all 128 flags (s_sleep backoff) -> __syncthreads
//             -> all threads stage h via b64 agent-scope bypassing loads.
__global__ __launch_bounds__(256) void rnn_layer(
    const float* __restrict__ Whh,   // [4096, 1024] f32
    const float* __restrict__ XP,    // [128*32, 4096] f32 (x-part + biases)
    const __bf16* __restrict__ h0,   // [32, 1024] initial h
    const float* __restrict__ c0,    // [32, 1024] initial c
    __bf16* __restrict__ hseq,       // [128*32, 1024] h outputs (t-major)
    float* __restrict__ cfin,        // [32, 1024] final c
    float* __restrict__ yout,        // nullptr or [B=32,T=128,H=1024] f32
    unsigned* __restrict__ flags) {  // [128] this layer's produce flags
  extern __shared__ char smem[];
  char*   sWc = smem;
  char*   sHc = smem + 65536;
  float*  sG  = (float*)(smem + 131072);           // [32][33] f32
  __bf16* sP  = (__bf16*)(smem + 131072 + 4352);   // [256] bf16 repack

  int tid = threadIdx.x;
  int blk = blockIdx.x;
  int lane = tid & 63, wave = tid >> 6;
  int mt = wave & 1, nt = wave >> 1;
  int frow = lane & 15;
  int kj = (lane >> 4) * 16;

  // ---- stage Whh slice once: 4 strips (i,f,g,o) of 8 contiguous rows each
  for (int g = 0; g < 4; ++g) {
    const float* sp = Whh + (size_t)(g * 1024 + blk * 8) * 1024;
#pragma unroll
    for (int it = 0; it < 8; ++it) {
      int e = (it * 256 + tid) * 4;
      int rl = e >> 10, k = e & 1023;
      float4 v = *(const float4*)(sp + e);
      bf16x4 t4;
      t4[0] = (__bf16)v.x; t4[1] = (__bf16)v.y; t4[2] = (__bf16)v.z; t4[3] = (__bf16)v.w;
      int r = g * 8 + rl;
      *(bf16x4*)(sWc + ((r << 11) + ((k << 1) ^ ((r & 7) << 4)))) = t4;
    }
  }

  // ---- per-thread cell state: thread owns (b = tid>>3, hl = tid&7)
  int hl = tid & 7, b = tid >> 3;
  float c = c0[b * 1024 + blk * 8 + hl];

  int ar = mt * 16 + frow, br = nt * 16 + frow;
  int asw = (ar & 7) << 4, bsw = (br & 7) << 4;
  const char* aRow = sHc + (ar << 11);
  const char* bRow = sWc + (br << 11);

  int jprod = tid >> 1;          // producer chunk this thread stages
  int rbase = (tid & 1) * 16;    // which 16 batch rows of it

  for (int t = 0; t < 128; ++t) {
    // ---- prefetch XP operands (independent of flags)
    const float* xr = XP + ((size_t)t * 32 + b) * 4096 + blk * 8 + hl;
    float xi = xr[0], xf = xr[1024], xg = xr[2048], xo = xr[3072];

    // ---- wave 0 polls all 128 producer flags with backoff
    if (t > 0 && wave == 0) {
      unsigned tt = (unsigned)t;
      for (;;) {
        bool ok =
            (__hip_atomic_load(flags + lane, __ATOMIC_RELAXED,
                               __HIP_MEMORY_SCOPE_AGENT) >= tt) &&
            (__hip_atomic_load(flags + 64 + lane, __ATOMIC_RELAXED,
                               __HIP_MEMORY_SCOPE_AGENT) >= tt);
        if (__all(ok)) break;
        __builtin_amdgcn_s_sleep(1);
      }
    }
    __syncthreads();

    // ---- stage h_{t-1} -> LDS via agent-scope bypassing b64 loads
    {
      const unsigned long long* src =
          (const unsigned long long*)((t == 0) ? h0
                                               : (hseq + (size_t)(t - 1) * 32 * 1024)) +
          jprod * 2;
      int csw = jprod * 16;   // byte col offset of this producer's chunk
#pragma unroll
      for (int r = 0; r < 16; ++r) {
        int row = rbase + r;
        unsigned long long lo = __hip_atomic_load(src + (size_t)row * 256,
                                                  __ATOMIC_RELAXED,
                                                  __HIP_MEMORY_SCOPE_AGENT);
        unsigned long long hi = __hip_atomic_load(src + (size_t)row * 256 + 1,
                                                  __ATOMIC_RELAXED,
                                                  __HIP_MEMORY_SCOPE_AGENT);
        u64x2 v; v[0] = lo; v[1] = hi;
        *(u64x2*)(sHc + ((row << 11) + (csw ^ ((row & 7) << 4)))) = v;
      }
    }
    __syncthreads();

    // ---- gates tile = h @ Whh_slice^T  (K = 1024)
    f32x4 acc = {0.f, 0.f, 0.f, 0.f};
#pragma unroll
    for (int kk = 0; kk < 32; ++kk) {
      int kb = kk * 64 + kj;
      bf16x8 a  = *(const bf16x8*)(aRow + (kb ^ asw));
      bf16x8 bv = *(const bf16x8*)(bRow + (kb ^ bsw));
      acc = __builtin_amdgcn_mfma_f32_16x16x32_bf16(a, bv, acc, 0, 0, 0);
    }

    // ---- dump accumulators to sG (stride 33 kills bank conflicts)
    {
      int col = nt * 16 + frow;
      int r0 = mt * 16 + ((lane >> 4) << 2);
      sG[(r0 + 0) * 33 + col] = acc[0];
      sG[(r0 + 1) * 33 + col] = acc[1];
      sG[(r0 + 2) * 33 + col] = acc[2];
      sG[(r0 + 3) * 33 + col] = acc[3];
    }
    __syncthreads();

    // ---- pointwise LSTM cell (f32), one (b, hcol) per thread
    float gi = sigmoidf_(sG[b * 33 + hl]      + xi);
    float gf = sigmoidf_(sG[b * 33 + 8 + hl]  + xf);
    float go = sigmoidf_(sG[b * 33 + 24 + hl] + xo);
    float gg = tanhf_(sG[b * 33 + 16 + hl]    + xg);
    c = gf * c + gi * gg;
    float h = go * tanhf_(c);
    if (yout) yout[((size_t)b * 128 + t) * 1024 + blk * 8 + hl] = h;
    sP[tid] = (__bf16)h;           // repack for 8B-granular publish
    __syncthreads();

    // ---- publish h_t: 64 threads, b64 agent-scope write-through stores
    if (tid < 64) {
      unsigned long long v = *(const unsigned long long*)(sP + tid * 4);
      unsigned long long* dst = (unsigned long long*)(
          hseq + ((size_t)t * 32 + (tid >> 1)) * 1024 + blk * 8 + (tid & 1) * 4);
      __hip_atomic_store(dst, v, __ATOMIC_RELAXED, __HIP_MEMORY_SCOPE_AGENT);
    }
    asm volatile("s_waitcnt vmcnt(0)" ::: "memory");
    __syncthreads();
    if (tid == 0)
      __hip_atomic_store(flags + blk, (unsigned)(t + 1), __ATOMIC_RELEASE,
                         __HIP_MEMORY_SCOPE_AGENT);
  }
  cfin[b * 1024 + blk * 8 + hl] = c;
}

// ---------------------------------------------------------------------------
extern "C" void kernel_launch(void* const* d_in, const int* in_sizes, int n_in,
                              void* d_out, int out_size, void* d_ws, size_t ws_size,
                              hipStream_t stream) {
  (void)in_sizes; (void)n_in; (void)out_size; (void)ws_size;
  const int*   src     = (const int*)d_in[0];
  const int*   tgt     = (const int*)d_in[1];
  const float* enc_emb = (const float*)d_in[2];
  const float* dec_emb = (const float*)d_in[3];
  const float* W[16];
  for (int i = 0; i < 16; ++i) W[i] = (const float*)d_in[4 + i];
  // enc: Wih0=W[0] Whh0=W[1] bih0=W[2] bhh0=W[3]  Wih1=W[4] Whh1=W[5] b=W[6],W[7]
  // dec: Wih0=W[8] Whh0=W[9] b=W[10],W[11]        Wih1=W[12] Whh1=W[13] b=W[14],W[15]

  char* ws = (char*)d_ws;
  size_t off = 0;
  auto alloc = [&](size_t bytes) {
    char* p = ws + off;
    off += (bytes + 255) & ~(size_t)255;
    return p;
  };
  unsigned* flags = (unsigned*)alloc(4 * 128 * sizeof(unsigned));
  float*    zeros = (float*)alloc((size_t)32 * 1024 * 4);       // h0/c0 zeros
  __bf16*   Xe   = (__bf16*)alloc((size_t)4096 * 512 * 2);
  __bf16*   Xd   = (__bf16*)alloc((size_t)4096 * 512 * 2);
  float*    XP   = (float*)alloc((size_t)4096 * 4096 * 4);      // reused x-part
  __bf16*   hE0  = (__bf16*)alloc((size_t)4096 * 1024 * 2);
  __bf16*   hE1  = (__bf16*)alloc((size_t)4096 * 1024 * 2);
  __bf16*   hD0  = (__bf16*)alloc((size_t)4096 * 1024 * 2);
  __bf16*   hD1  = (__bf16*)alloc((size_t)4096 * 1024 * 2);
  float*    cE0  = (float*)alloc((size_t)32 * 1024 * 4);
  float*    cE1  = (float*)alloc((size_t)32 * 1024 * 4);
  float*    cdum = (float*)alloc((size_t)32 * 1024 * 4);

  hipFuncSetAttribute((const void*)rnn_layer,
                      hipFuncAttributeMaxDynamicSharedMemorySize, RNN_SMEM);

  init_ws<<<128, 256, 0, stream>>>(zeros, flags);
  gather_emb<<<8192, 128, 0, stream>>>(src, tgt, enc_emb, dec_emb, Xe, Xd);

  // encoder L0
  gemm_xp<<<1024, 256, 0, stream>>>(Xe, W[0], W[2], W[3], XP, 512);
  rnn_layer<<<RNN_BLOCKS, 256, RNN_SMEM, stream>>>(
      W[1], XP, (const __bf16*)zeros, zeros, hE0, cE0, nullptr, flags + 0);
  // encoder L1
  gemm_xp<<<1024, 256, 0, stream>>>(hE0, W[4], W[6], W[7], XP, 1024);
  rnn_layer<<<RNN_BLOCKS, 256, RNN_SMEM, stream>>>(
      W[5], XP, (const __bf16*)zeros, zeros, hE1, cE1, nullptr, flags + 128);
  // decoder L0 (init = enc L0 finals)
  gemm_xp<<<1024, 256, 0, stream>>>(Xd, W[8], W[10], W[11], XP, 512);
  rnn_layer<<<RNN_BLOCKS, 256, RNN_SMEM, stream>>>(
      W[9], XP, hE0 + (size_t)127 * 32 * 1024, cE0, hD0, cdum, nullptr, flags + 256);
  // decoder L1 (init = enc L1 finals) -> writes d_out f32 [B,T,H]
  gemm_xp<<<1024, 256, 0, stream>>>(hD0, W[12], W[14], W[15], XP, 1024);
  rnn_layer<<<RNN_BLOCKS, 256, RNN_SMEM, stream>>>(
      W[13], XP, hE1 + (size_t)127 * 32 * 1024, cE1, hD1, cdum, (float*)d_out, flags + 384);
}

// Round 4
// 4634.397 us; speedup vs baseline: 1.4283x; 1.2801x over previous
//
#include <hip/hip_runtime.h>
#include <hip/hip_bf16.h>
#include <stdint.h>

// ---------------------------------------------------------------------------
// Seq2seq LSTM (2-layer enc + 2-layer dec, B=32, S=T=128, E=512, H=1024).
//   1. gather_emb: embedding lookup -> bf16 X (t-major rows: row = t*32+b)
//   2. gemm_xp:    XP = X @ Wih^T + (bih+bhh)  (bf16 out, f32 accumulate)
//   3. rnn_kernel: persistent 1-block/CU kernel; Whh (bf16) resident in LDS.
//      h slab layout per step: [producer j=128][b=32][8 cols] bf16 -- every
//      128B line belongs to ONE producer, so consumers may use plain
//      coalesced b128 loads (L2-shared within an XCD) with NO per-step
//      fence; freshness comes from flag-after-writethrough + start fence.
//   Epochs: encL0 (128) -> [encL1 || decL0 fused, 256 blocks] (128)
//           -> decL1 (128)  = 384 sequential steps instead of 512.
// ---------------------------------------------------------------------------

typedef __attribute__((ext_vector_type(8))) __bf16 bf16x8;
typedef __attribute__((ext_vector_type(4))) __bf16 bf16x4;
typedef __attribute__((ext_vector_type(4))) float  f32x4;

#define RNN_SMEM (65536 + 65536 + 6144)
#define SLAB 32768   // bf16 elems per h slab: [128 j][32 b][8 col] = 64KB

__device__ __forceinline__ float sigmoidf_(float x) {
  return 1.f / (1.f + __expf(-x));
}
__device__ __forceinline__ float tanhf_(float x) {
  float e = __expf(-2.f * fabsf(x));
  float t = (1.f - e) / (1.f + e);
  return x < 0.f ? -t : t;
}

// ---------------------------------------------------------------------------
__global__ void init_ws(float* zeros, unsigned* flags) {
  int i = blockIdx.x * 256 + threadIdx.x;
  if (i < 32 * 1024) zeros[i] = 0.f;
  if (i < 512) flags[i] = 0u;          // 4 layers x 128 producer flags
}

// ---------------------------------------------------------------------------
__global__ void gather_emb(const int* __restrict__ src, const int* __restrict__ tgt,
                           const float* __restrict__ ee, const float* __restrict__ de,
                           __bf16* __restrict__ Xe, __bf16* __restrict__ Xd) {
  int row = blockIdx.x & 4095;
  int t = row >> 5, b = row & 31;
  bool isd = blockIdx.x >= 4096;
  int tok = isd ? (t == 0 ? 1 : tgt[b * 128 + t - 1]) : src[b * 128 + t];
  const float* ep = (isd ? de : ee) + (size_t)tok * 512;
  __bf16* op = (isd ? Xd : Xe) + (size_t)row * 512;
  int i = threadIdx.x * 4;
  float4 v = *(const float4*)(ep + i);
  bf16x4 t4;
  t4[0] = (__bf16)v.x; t4[1] = (__bf16)v.y; t4[2] = (__bf16)v.z; t4[3] = (__bf16)v.w;
  *(bf16x4*)(op + i) = t4;
}

// ---------------------------------------------------------------------------
// XP[M=4096, N=4096] = A[M,K](bf16) @ W[N,K]^T(f32->bf16) + bih + bhh.
// Output bf16 (f32 accumulate). chunked=1: A rows live in h-slab layout
// (row = t*32+b, elem k at A[t*SLAB + (k>>3)*256 + b*8 + (k&7)]).
__global__ __launch_bounds__(256) void gemm_xp(
    const __bf16* __restrict__ A, const float* __restrict__ W,
    const float* __restrict__ bih, const float* __restrict__ bhh,
    __bf16* __restrict__ C, int K, int chunked) {
  __shared__ char sA[128 * 64 * 2];
  __shared__ char sB[128 * 64 * 2];
  int tid = threadIdx.x;
  int lane = tid & 63, wave = tid >> 6;
  int wm = wave & 1, wn = wave >> 1;
  int bm = blockIdx.x & 31, bn = blockIdx.x >> 5;
  int frow = lane & 15;
  int kj = (lane >> 4) * 16;

  f32x4 acc[4][4] = {};

  for (int k0 = 0; k0 < K; k0 += 64) {
#pragma unroll
    for (int c4 = 0; c4 < 4; ++c4) {   // stage A tile (bf16, swizzled)
      int idx = (c4 * 256 + tid) * 8;
      int r = idx >> 6, kk = idx & 63;
      int gr = bm * 128 + r;
      const __bf16* ap;
      if (chunked) {
        int tt = gr >> 5, bb = gr & 31;
        ap = A + (size_t)tt * SLAB + ((k0 + kk) >> 3) * 256 + bb * 8;
      } else {
        ap = A + (size_t)gr * K + k0 + kk;
      }
      bf16x8 v = *(const bf16x8*)ap;
      *(bf16x8*)(sA + ((r * 128 + kk * 2) ^ ((r & 7) << 4))) = v;
    }
#pragma unroll
    for (int c4 = 0; c4 < 4; ++c4) {   // stage B tile (f32 -> bf16, swizzled)
      int idx = (c4 * 256 + tid) * 8;
      int r = idx >> 6, kk = idx & 63;
      const float* wp = W + (size_t)(bn * 128 + r) * K + k0 + kk;
      float4 w0 = *(const float4*)wp;
      float4 w1 = *(const float4*)(wp + 4);
      bf16x8 v;
      v[0] = (__bf16)w0.x; v[1] = (__bf16)w0.y; v[2] = (__bf16)w0.z; v[3] = (__bf16)w0.w;
      v[4] = (__bf16)w1.x; v[5] = (__bf16)w1.y; v[6] = (__bf16)w1.z; v[7] = (__bf16)w1.w;
      *(bf16x8*)(sB + ((r * 128 + kk * 2) ^ ((r & 7) << 4))) = v;
    }
    __syncthreads();
#pragma unroll
    for (int half = 0; half < 2; ++half) {
      int kb = half * 64 + kj;
      bf16x8 af[4], bfr[4];
#pragma unroll
      for (int f = 0; f < 4; ++f) {
        int arr = wm * 64 + f * 16 + frow;
        af[f] = *(const bf16x8*)(sA + (arr * 128 + (kb ^ ((arr & 7) << 4))));
        int brr = wn * 64 + f * 16 + frow;
        bfr[f] = *(const bf16x8*)(sB + (brr * 128 + (kb ^ ((brr & 7) << 4))));
      }
#pragma unroll
      for (int fm = 0; fm < 4; ++fm)
#pragma unroll
        for (int fn = 0; fn < 4; ++fn)
          acc[fm][fn] = __builtin_amdgcn_mfma_f32_16x16x32_bf16(af[fm], bfr[fn],
                                                                acc[fm][fn], 0, 0, 0);
    }
    __syncthreads();
  }
  int cm = bm * 128 + wm * 64, cn = bn * 128 + wn * 64;
#pragma unroll
  for (int fn = 0; fn < 4; ++fn) {
    int col = cn + fn * 16 + frow;
    float bias = bih[col] + bhh[col];
#pragma unroll
    for (int fm = 0; fm < 4; ++fm) {
      int r0 = cm + fm * 16 + ((lane >> 4) << 2);
#pragma unroll
      for (int j = 0; j < 4; ++j)
        C[(size_t)(r0 + j) * 4096 + col] = (__bf16)(acc[fm][fn][j] + bias);
    }
  }
}

// ---------------------------------------------------------------------------
struct RnnArgs {
  const float* Whh;    // [4096, 1024] f32
  const __bf16* XP;    // [128*32, 4096] bf16 (x-part + biases)
  const __bf16* h0;    // [SLAB] initial h in slab layout (or zeros)
  const float* c0;     // [32, 1024] initial c
  __bf16* hseq;        // [128][SLAB] h slabs
  float* cfin;         // [32, 1024] final c
  float* yout;         // nullptr or [B,T,H] f32 output
  unsigned* flags;     // [128] produce flags
};

__device__ __forceinline__ void rnn_body(const RnnArgs& P, int blk, char* smem) {
  char*   sWc = smem;
  char*   sHc = smem + 65536;
  float*  sG  = (float*)(smem + 131072);           // [32][33]
  __bf16* sP  = (__bf16*)(smem + 131072 + 4352);   // [256]

  int tid = threadIdx.x;
  int lane = tid & 63, wave = tid >> 6;
  int mt = wave & 1, nt = wave >> 1;
  int frow = lane & 15;
  int kj = (lane >> 4) * 16;

  // one-time invalidate: kill any stale L1/L2 lines from previous replays
  __builtin_amdgcn_fence(__ATOMIC_ACQUIRE, "agent");

  // ---- stage Whh slice once: 4 strips (i,f,g,o) of 8 contiguous rows each
  for (int g = 0; g < 4; ++g) {
    const float* sp = P.Whh + (size_t)(g * 1024 + blk * 8) * 1024;
#pragma unroll
    for (int it = 0; it < 8; ++it) {
      int e = (it * 256 + tid) * 4;
      int rl = e >> 10, k = e & 1023;
      float4 v = *(const float4*)(sp + e);
      bf16x4 t4;
      t4[0] = (__bf16)v.x; t4[1] = (__bf16)v.y; t4[2] = (__bf16)v.z; t4[3] = (__bf16)v.w;
      int r = g * 8 + rl;
      *(bf16x4*)(sWc + ((r << 11) + ((k << 1) ^ ((r & 7) << 4)))) = t4;
    }
  }

  int hl = tid & 7, b = tid >> 3;
  float c = P.c0[b * 1024 + blk * 8 + hl];

  int ar = mt * 16 + frow, br = nt * 16 + frow;
  int asw = (ar & 7) << 4, bsw = (br & 7) << 4;
  const char* aRow = sHc + (ar << 11);
  const char* bRow = sWc + (br << 11);

  for (int t = 0; t < 128; ++t) {
    // ---- prefetch XP operands (bf16, independent of flags)
    const __bf16* xr = P.XP + ((size_t)t * 32 + b) * 4096 + blk * 8 + hl;
    float xi = (float)xr[0], xf = (float)xr[1024];
    float xg = (float)xr[2048], xo = (float)xr[3072];

    // ---- wave 0 polls all 128 producer flags
    if (t > 0 && wave == 0) {
      unsigned tt = (unsigned)t;
      for (;;) {
        bool ok =
            (__hip_atomic_load(P.flags + lane, __ATOMIC_RELAXED,
                               __HIP_MEMORY_SCOPE_AGENT) >= tt) &&
            (__hip_atomic_load(P.flags + 64 + lane, __ATOMIC_RELAXED,
                               __HIP_MEMORY_SCOPE_AGENT) >= tt);
        if (__all(ok)) break;
        __builtin_amdgcn_s_sleep(1);
      }
    }
    __syncthreads();

    // ---- stage h_{t-1} -> LDS: plain coalesced b128 loads (L2-shared/XCD)
    {
      const char* hb = (const char*)((t == 0) ? P.h0
                                              : (P.hseq + (size_t)(t - 1) * SLAB));
#pragma unroll
      for (int it = 0; it < 16; ++it) {
        int idx = it * 256 + tid;
        int j = idx >> 5, bb = idx & 31;   // producer chunk j, batch row bb
        bf16x8 v = *(const bf16x8*)(hb + j * 512 + bb * 16);
        *(bf16x8*)(sHc + ((bb << 11) + ((j * 16) ^ ((bb & 7) << 4)))) = v;
      }
    }
    __syncthreads();

    // ---- gates tile = h @ Whh_slice^T  (K = 1024)
    f32x4 acc = {0.f, 0.f, 0.f, 0.f};
#pragma unroll
    for (int kk = 0; kk < 32; ++kk) {
      int kb = kk * 64 + kj;
      bf16x8 a  = *(const bf16x8*)(aRow + (kb ^ asw));
      bf16x8 bv = *(const bf16x8*)(bRow + (kb ^ bsw));
      acc = __builtin_amdgcn_mfma_f32_16x16x32_bf16(a, bv, acc, 0, 0, 0);
    }
    {
      int col = nt * 16 + frow;
      int r0 = mt * 16 + ((lane >> 4) << 2);
      sG[(r0 + 0) * 33 + col] = acc[0];
      sG[(r0 + 1) * 33 + col] = acc[1];
      sG[(r0 + 2) * 33 + col] = acc[2];
      sG[(r0 + 3) * 33 + col] = acc[3];
    }
    __syncthreads();

    // ---- pointwise LSTM cell (f32), one (b, hcol) per thread
    float gi = sigmoidf_(sG[b * 33 + hl]      + xi);
    float gf = sigmoidf_(sG[b * 33 + 8 + hl]  + xf);
    float go = sigmoidf_(sG[b * 33 + 24 + hl] + xo);
    float gg = tanhf_(sG[b * 33 + 16 + hl]    + xg);
    c = gf * c + gi * gg;
    float h = go * tanhf_(c);
    if (P.yout) P.yout[((size_t)b * 128 + t) * 1024 + blk * 8 + hl] = h;
    sP[tid] = (__bf16)h;           // repack [32][8] for publish
    __syncthreads();

    // ---- publish: wave 0 writes this block's 512B chunk write-through,
    //      drains vmcnt, then releases the flag (program order, same wave)
    if (tid < 64) {
      unsigned long long v = *(const unsigned long long*)(sP + tid * 4);
      unsigned long long* dst = (unsigned long long*)(
          (char*)P.hseq + (size_t)t * 65536 + blk * 512 + tid * 8);
      __hip_atomic_store(dst, v, __ATOMIC_RELAXED, __HIP_MEMORY_SCOPE_AGENT);
      asm volatile("s_waitcnt vmcnt(0)" ::: "memory");
      if (tid == 0)
        __hip_atomic_store(P.flags + blk, (unsigned)(t + 1), __ATOMIC_RELEASE,
                           __HIP_MEMORY_SCOPE_AGENT);
    }
  }
  P.cfin[b * 1024 + blk * 8 + hl] = c;
}

// Blocks 0-127 run layer A; blocks 128-255 run layer B (independent layers).
__global__ __launch_bounds__(256) void rnn_kernel(RnnArgs A, RnnArgs B) {
  extern __shared__ char smem[];
  if (blockIdx.x < 128) rnn_body(A, blockIdx.x, smem);
  else                  rnn_body(B, blockIdx.x - 128, smem);
}

// ---------------------------------------------------------------------------
extern "C" void kernel_launch(void* const* d_in, const int* in_sizes, int n_in,
                              void* d_out, int out_size, void* d_ws, size_t ws_size,
                              hipStream_t stream) {
  (void)in_sizes; (void)n_in; (void)out_size; (void)ws_size;
  const int*   src     = (const int*)d_in[0];
  const int*   tgt     = (const int*)d_in[1];
  const float* enc_emb = (const float*)d_in[2];
  const float* dec_emb = (const float*)d_in[3];
  const float* W[16];
  for (int i = 0; i < 16; ++i) W[i] = (const float*)d_in[4 + i];
  // enc: Wih0=W[0] Whh0=W[1] bih0=W[2] bhh0=W[3]  Wih1=W[4] Whh1=W[5] b=W[6],W[7]
  // dec: Wih0=W[8] Whh0=W[9] b=W[10],W[11]        Wih1=W[12] Whh1=W[13] b=W[14],W[15]

  char* ws = (char*)d_ws;
  size_t off = 0;
  auto alloc = [&](size_t bytes) {
    char* p = ws + off;
    off += (bytes + 255) & ~(size_t)255;
    return p;
  };
  unsigned* flags = (unsigned*)alloc(4 * 128 * sizeof(unsigned));
  float*    zeros = (float*)alloc((size_t)32 * 1024 * 4);
  __bf16*   Xe   = (__bf16*)alloc((size_t)4096 * 512 * 2);
  __bf16*   Xd   = (__bf16*)alloc((size_t)4096 * 512 * 2);
  __bf16*   XP1  = (__bf16*)alloc((size_t)4096 * 4096 * 2);
  __bf16*   XP2  = (__bf16*)alloc((size_t)4096 * 4096 * 2);
  __bf16*   hE0  = (__bf16*)alloc((size_t)128 * SLAB * 2);
  __bf16*   hE1  = (__bf16*)alloc((size_t)128 * SLAB * 2);
  __bf16*   hD0  = (__bf16*)alloc((size_t)128 * SLAB * 2);
  __bf16*   hD1  = (__bf16*)alloc((size_t)128 * SLAB * 2);
  float*    cE0  = (float*)alloc((size_t)32 * 1024 * 4);
  float*    cE1  = (float*)alloc((size_t)32 * 1024 * 4);
  float*    cdum = (float*)alloc((size_t)32 * 1024 * 4);

  hipFuncSetAttribute((const void*)rnn_kernel,
                      hipFuncAttributeMaxDynamicSharedMemorySize, RNN_SMEM);

  init_ws<<<128, 256, 0, stream>>>(zeros, flags);
  gather_emb<<<8192, 128, 0, stream>>>(src, tgt, enc_emb, dec_emb, Xe, Xd);

  // encoder L0 (solo)
  gemm_xp<<<1024, 256, 0, stream>>>(Xe, W[0], W[2], W[3], XP1, 512, 0);
  RnnArgs e0{W[1], XP1, (const __bf16*)zeros, zeros, hE0, cE0, nullptr, flags + 0};
  rnn_kernel<<<128, 256, RNN_SMEM, stream>>>(e0, e0);

  // XP for encoder L1 (from hE0, chunked) reuses XP1; XP for decoder L0 -> XP2
  gemm_xp<<<1024, 256, 0, stream>>>(hE0, W[4], W[6], W[7], XP1, 1024, 1);
  gemm_xp<<<1024, 256, 0, stream>>>(Xd, W[8], W[10], W[11], XP2, 512, 0);

  // fused: encoder L1 (blocks 0-127) || decoder L0 (blocks 128-255)
  RnnArgs e1{W[5], XP1, (const __bf16*)zeros, zeros, hE1, cE1, nullptr, flags + 128};
  RnnArgs d0{W[9], XP2, hE0 + (size_t)127 * SLAB, cE0, hD0, cdum, nullptr, flags + 256};
  rnn_kernel<<<256, 256, RNN_SMEM, stream>>>(e1, d0);

  // decoder L1 (solo) -> writes d_out f32 [B,T,H]
  gemm_xp<<<1024, 256, 0, stream>>>(hD0, W[12], W[14], W[15], XP1, 1024, 1);
  RnnArgs d1{W[13], XP1, hE1 + (size_t)127 * SLAB, cE1, hD1, cdum, (float*)d_out,
             flags + 384};
  rnn_kernel<<<128, 256, RNN_SMEM, stream>>>(d1, d1);
}

// Round 5
// 2432.575 us; speedup vs baseline: 2.7211x; 1.9051x over previous
//
#include <hip/hip_runtime.h>
#include <hip/hip_bf16.h>
#include <stdint.h>

// ---------------------------------------------------------------------------
// Seq2seq LSTM (2-layer enc + 2-layer dec, B=32, S=T=128, E=512, H=1024).
//   gather_emb -> bf16 X;  gemm_xp: XP = X @ Wih0^T + bias (bf16, layer-0 only)
//   rnn_pair: ONE dispatch per enc/dec, 256 blocks:
//     blocks 0-127  = layer0: gates = h0_{t-1} @ Whh^T + XP[t]
//     blocks 128-255= layer1: gates = h0_t @ Wih^T + h1_{t-1} @ Whh^T + bias
//     (1-step skew; layer0 runs ahead, layer1 polls both flag arrays)
//   h transport: slab layout [t][producer j=128][b=32][8 cols] bf16; producers
//   publish 512B chunks write-through (agent atomics) then release a flag;
//   consumers read MFMA A-fragments DIRECTLY from the slab (coalesced 256B
//   groups, L2-shared per XCD) -- no per-step LDS staging, no per-step fence.
// Sequential grid-sync epochs: 256 (was 384).
// ---------------------------------------------------------------------------

typedef __attribute__((ext_vector_type(8))) __bf16 bf16x8;
typedef __attribute__((ext_vector_type(4))) __bf16 bf16x4;
typedef __attribute__((ext_vector_type(4))) float  f32x4;

#define SLAB 32768   // bf16 elems per h slab: [128 j][32 b][8 col] = 64KB
// LDS: Wxh slice 64KB + Whh slice 64KB + sG (32x33 f32) + sP (256 bf16)
#define RNN_SMEM (65536 + 65536 + 4352 + 512)

__device__ __forceinline__ float sigmoidf_(float x) {
  return 1.f / (1.f + __expf(-x));
}
__device__ __forceinline__ float tanhf_(float x) {
  float e = __expf(-2.f * fabsf(x));
  float t = (1.f - e) / (1.f + e);
  return x < 0.f ? -t : t;
}

// ---------------------------------------------------------------------------
__global__ void init_ws(float* zeros, unsigned* flags) {
  int i = blockIdx.x * 256 + threadIdx.x;
  if (i < 32 * 1024) zeros[i] = 0.f;
  if (i < 512) flags[i] = 0u;          // 4 layers x 128 producer flags
}

// ---------------------------------------------------------------------------
__global__ void gather_emb(const int* __restrict__ src, const int* __restrict__ tgt,
                           const float* __restrict__ ee, const float* __restrict__ de,
                           __bf16* __restrict__ Xe, __bf16* __restrict__ Xd) {
  int row = blockIdx.x & 4095;
  int t = row >> 5, b = row & 31;
  bool isd = blockIdx.x >= 4096;
  int tok = isd ? (t == 0 ? 1 : tgt[b * 128 + t - 1]) : src[b * 128 + t];
  const float* ep = (isd ? de : ee) + (size_t)tok * 512;
  __bf16* op = (isd ? Xd : Xe) + (size_t)row * 512;
  int i = threadIdx.x * 4;
  float4 v = *(const float4*)(ep + i);
  bf16x4 t4;
  t4[0] = (__bf16)v.x; t4[1] = (__bf16)v.y; t4[2] = (__bf16)v.z; t4[3] = (__bf16)v.w;
  *(bf16x4*)(op + i) = t4;
}

// ---------------------------------------------------------------------------
// XP[M=4096, N=4096] = A[M,K=512](bf16) @ W[N,K]^T(f32->bf16) + bih + bhh.
__global__ __launch_bounds__(256) void gemm_xp(
    const __bf16* __restrict__ A, const float* __restrict__ W,
    const float* __restrict__ bih, const float* __restrict__ bhh,
    __bf16* __restrict__ C, int K) {
  __shared__ char sA[128 * 64 * 2];
  __shared__ char sB[128 * 64 * 2];
  int tid = threadIdx.x;
  int lane = tid & 63, wave = tid >> 6;
  int wm = wave & 1, wn = wave >> 1;
  int bm = blockIdx.x & 31, bn = blockIdx.x >> 5;
  int frow = lane & 15;
  int kj = (lane >> 4) * 16;

  f32x4 acc[4][4] = {};

  for (int k0 = 0; k0 < K; k0 += 64) {
#pragma unroll
    for (int c4 = 0; c4 < 4; ++c4) {   // stage A tile (bf16, swizzled)
      int idx = (c4 * 256 + tid) * 8;
      int r = idx >> 6, kk = idx & 63;
      bf16x8 v = *(const bf16x8*)(A + (size_t)(bm * 128 + r) * K + k0 + kk);
      *(bf16x8*)(sA + ((r * 128 + kk * 2) ^ ((r & 7) << 4))) = v;
    }
#pragma unroll
    for (int c4 = 0; c4 < 4; ++c4) {   // stage B tile (f32 -> bf16, swizzled)
      int idx = (c4 * 256 + tid) * 8;
      int r = idx >> 6, kk = idx & 63;
      const float* wp = W + (size_t)(bn * 128 + r) * K + k0 + kk;
      float4 w0 = *(const float4*)wp;
      float4 w1 = *(const float4*)(wp + 4);
      bf16x8 v;
      v[0] = (__bf16)w0.x; v[1] = (__bf16)w0.y; v[2] = (__bf16)w0.z; v[3] = (__bf16)w0.w;
      v[4] = (__bf16)w1.x; v[5] = (__bf16)w1.y; v[6] = (__bf16)w1.z; v[7] = (__bf16)w1.w;
      *(bf16x8*)(sB + ((r * 128 + kk * 2) ^ ((r & 7) << 4))) = v;
    }
    __syncthreads();
#pragma unroll
    for (int half = 0; half < 2; ++half) {
      int kb = half * 64 + kj;
      bf16x8 af[4], bfr[4];
#pragma unroll
      for (int f = 0; f < 4; ++f) {
        int arr = wm * 64 + f * 16 + frow;
        af[f] = *(const bf16x8*)(sA + (arr * 128 + (kb ^ ((arr & 7) << 4))));
        int brr = wn * 64 + f * 16 + frow;
        bfr[f] = *(const bf16x8*)(sB + (brr * 128 + (kb ^ ((brr & 7) << 4))));
      }
#pragma unroll
      for (int fm = 0; fm < 4; ++fm)
#pragma unroll
        for (int fn = 0; fn < 4; ++fn)
          acc[fm][fn] = __builtin_amdgcn_mfma_f32_16x16x32_bf16(af[fm], bfr[fn],
                                                                acc[fm][fn], 0, 0, 0);
    }
    __syncthreads();
  }
  int cm = bm * 128 + wm * 64, cn = bn * 128 + wn * 64;
#pragma unroll
  for (int fn = 0; fn < 4; ++fn) {
    int col = cn + fn * 16 + frow;
    float bias = bih[col] + bhh[col];
#pragma unroll
    for (int fm = 0; fm < 4; ++fm) {
      int r0 = cm + fm * 16 + ((lane >> 4) << 2);
#pragma unroll
      for (int j = 0; j < 4; ++j)
        C[(size_t)(r0 + j) * 4096 + col] = (__bf16)(acc[fm][fn][j] + bias);
    }
  }
}

// ---------------------------------------------------------------------------
struct RnnArgs {
  const float* Whh;       // [4096,1024] recurrent weights (f32)
  const float* Wxh;       // layer1: [4096,1024] input weights; layer0: nullptr
  const float* bih;       // layer1 bias (layer0: baked into XP)
  const float* bhh;
  const __bf16* XP;       // layer0: [128*32][4096] x-part+bias; layer1: nullptr
  const __bf16* xslab;    // layer1: [128][SLAB] lower layer's h slabs
  const unsigned* xflags; // layer1: lower layer's flags
  const __bf16* h0;       // [SLAB] initial h (slab layout)
  const float* c0;        // [32*1024] initial c
  __bf16* hseq;           // [128][SLAB]
  float* cfin;            // [32*1024]
  float* yout;            // nullptr or [B,T,H] f32
  unsigned* flags;        // [128] own produce flags
};

// K=1024 accumulate: A-frags straight from a global h slab, B from LDS.
__device__ __forceinline__ f32x4 accum_k1024(f32x4 acc, const char* abase,
                                             const char* bRow, int bsw, int kj) {
#pragma unroll
  for (int kt = 0; kt < 32; kt += 8) {
    bf16x8 af[8];
#pragma unroll
    for (int u = 0; u < 8; ++u)
      af[u] = *(const bf16x8*)(abase + (size_t)(kt + u) * 2048);
#pragma unroll
    for (int u = 0; u < 8; ++u) {
      int kb = (kt + u) * 64 + kj;
      bf16x8 bv = *(const bf16x8*)(bRow + (kb ^ bsw));
      acc = __builtin_amdgcn_mfma_f32_16x16x32_bf16(af[u], bv, acc, 0, 0, 0);
    }
  }
  return acc;
}

__device__ __forceinline__ void rnn_body(const RnnArgs& P, int blk, char* smem) {
  char*   sW0 = smem;                              // Wxh slice (layer1)
  char*   sW1 = smem + 65536;                      // Whh slice
  float*  sG  = (float*)(smem + 131072);           // [32][33]
  __bf16* sP  = (__bf16*)(smem + 131072 + 4352);   // [256]

  int tid = threadIdx.x;
  int lane = tid & 63, wave = tid >> 6;
  int mt = wave & 1, nt = wave >> 1;
  int frow = lane & 15;
  int kj = (lane >> 4) * 16;
  bool isL0 = (P.XP != nullptr);

  // one-time invalidate: kill stale L1/L2 lines from previous graph replays
  __builtin_amdgcn_fence(__ATOMIC_ACQUIRE, "agent");

  // ---- stage weight slices once (f32 -> bf16, swizzled rows of 1024)
  {
    const float* srcs[2] = {P.Wxh, P.Whh};
    char* dsts[2] = {sW0, sW1};
    for (int s = (isL0 ? 1 : 0); s < 2; ++s) {
      for (int g = 0; g < 4; ++g) {
        const float* sp = srcs[s] + (size_t)(g * 1024 + blk * 8) * 1024;
#pragma unroll
        for (int it = 0; it < 8; ++it) {
          int e = (it * 256 + tid) * 4;
          int rl = e >> 10, k = e & 1023;
          float4 v = *(const float4*)(sp + e);
          bf16x4 t4;
          t4[0] = (__bf16)v.x; t4[1] = (__bf16)v.y;
          t4[2] = (__bf16)v.z; t4[3] = (__bf16)v.w;
          int r = g * 8 + rl;
          *(bf16x4*)(dsts[s] + ((r << 11) + ((k << 1) ^ ((r & 7) << 4)))) = t4;
        }
      }
    }
  }

  int hl = tid & 7, b = tid >> 3;
  float c = P.c0[b * 1024 + blk * 8 + hl];

  // layer1: per-thread gate biases (layer0 has them baked into XP)
  float bI = 0.f, bF = 0.f, bG = 0.f, bO = 0.f;
  if (!isL0) {
    int col = blk * 8 + hl;
    bI = P.bih[col] + P.bhh[col];
    bF = P.bih[1024 + col] + P.bhh[1024 + col];
    bG = P.bih[2048 + col] + P.bhh[2048 + col];
    bO = P.bih[3072 + col] + P.bhh[3072 + col];
  }

  int abrow = mt * 16 + frow;                  // A-operand batch row
  int aoff = (lane >> 4) * 512 + abrow * 16;   // byte offset within a slab
  int br = nt * 16 + frow, bsw = (br & 7) << 4;
  const char* bRow0 = sW0 + (br << 11);
  const char* bRow1 = sW1 + (br << 11);

  for (int t = 0; t < 128; ++t) {
    float xi = bI, xf = bF, xg = bG, xo = bO;
    if (isL0) {   // prefetch XP operands before the poll
      const __bf16* xr = P.XP + ((size_t)t * 32 + b) * 4096 + blk * 8 + hl;
      xi = (float)xr[0]; xf = (float)xr[1024];
      xg = (float)xr[2048]; xo = (float)xr[3072];
    }

    // ---- wave 0 polls producer flags (own layer t-1; lower layer t)
    if (wave == 0 && (t > 0 || !isL0)) {
      unsigned th = (unsigned)t, tx = (unsigned)(t + 1);
      for (;;) {
        bool ok = true;
        if (!isL0)
          ok = (__hip_atomic_load(P.xflags + lane, __ATOMIC_RELAXED,
                                  __HIP_MEMORY_SCOPE_AGENT) >= tx) &&
               (__hip_atomic_load(P.xflags + 64 + lane, __ATOMIC_RELAXED,
                                  __HIP_MEMORY_SCOPE_AGENT) >= tx);
        if (t > 0)
          ok = ok &&
               (__hip_atomic_load(P.flags + lane, __ATOMIC_RELAXED,
                                  __HIP_MEMORY_SCOPE_AGENT) >= th) &&
               (__hip_atomic_load(P.flags + 64 + lane, __ATOMIC_RELAXED,
                                  __HIP_MEMORY_SCOPE_AGENT) >= th);
        if (__all(ok)) break;
        __builtin_amdgcn_s_sleep(1);
      }
    }
    __syncthreads();

    // ---- gates = [x-part] + h_{t-1} @ Whh^T   (A-frags direct from global)
    f32x4 acc = {0.f, 0.f, 0.f, 0.f};
    if (!isL0) {
      const char* xa = (const char*)(P.xslab + (size_t)t * SLAB) + aoff;
      acc = accum_k1024(acc, xa, bRow0, bsw, kj);
    }
    {
      const char* ha = (const char*)((t == 0) ? P.h0
                                              : (P.hseq + (size_t)(t - 1) * SLAB)) + aoff;
      acc = accum_k1024(acc, ha, bRow1, bsw, kj);
    }

    // ---- dump accumulators to sG (stride 33: conflict-free)
    {
      int col = nt * 16 + frow;
      int r0 = mt * 16 + ((lane >> 4) << 2);
      sG[(r0 + 0) * 33 + col] = acc[0];
      sG[(r0 + 1) * 33 + col] = acc[1];
      sG[(r0 + 2) * 33 + col] = acc[2];
      sG[(r0 + 3) * 33 + col] = acc[3];
    }
    __syncthreads();

    // ---- pointwise LSTM cell (f32), one (b, hcol) per thread
    float gi = sigmoidf_(sG[b * 33 + hl]      + xi);
    float gf = sigmoidf_(sG[b * 33 + 8 + hl]  + xf);
    float go = sigmoidf_(sG[b * 33 + 24 + hl] + xo);
    float gg = tanhf_(sG[b * 33 + 16 + hl]    + xg);
    c = gf * c + gi * gg;
    float h = go * tanhf_(c);
    if (P.yout) P.yout[((size_t)b * 128 + t) * 1024 + blk * 8 + hl] = h;
    sP[tid] = (__bf16)h;
    __syncthreads();

    // ---- publish: wave 0 writes 512B chunk write-through, drains, flags
    if (tid < 64) {
      unsigned long long v = *(const unsigned long long*)(sP + tid * 4);
      unsigned long long* dst = (unsigned long long*)(
          (char*)P.hseq + (size_t)t * 65536 + blk * 512 + tid * 8);
      __hip_atomic_store(dst, v, __ATOMIC_RELAXED, __HIP_MEMORY_SCOPE_AGENT);
      asm volatile("s_waitcnt vmcnt(0)" ::: "memory");
      if (tid == 0)
        __hip_atomic_store(P.flags + blk, (unsigned)(t + 1), __ATOMIC_RELEASE,
                           __HIP_MEMORY_SCOPE_AGENT);
    }
  }
  P.cfin[b * 1024 + blk * 8 + hl] = c;
}

// Blocks 0-127: layer0 (A). Blocks 128-255: layer1 (B), 1-step skewed.
__global__ __launch_bounds__(256) void rnn_pair(RnnArgs A, RnnArgs B) {
  extern __shared__ char smem[];
  if (blockIdx.x < 128) rnn_body(A, blockIdx.x, smem);
  else                  rnn_body(B, blockIdx.x - 128, smem);
}

// ---------------------------------------------------------------------------
extern "C" void kernel_launch(void* const* d_in, const int* in_sizes, int n_in,
                              void* d_out, int out_size, void* d_ws, size_t ws_size,
                              hipStream_t stream) {
  (void)in_sizes; (void)n_in; (void)out_size; (void)ws_size;
  const int*   src     = (const int*)d_in[0];
  const int*   tgt     = (const int*)d_in[1];
  const float* enc_emb = (const float*)d_in[2];
  const float* dec_emb = (const float*)d_in[3];
  const float* W[16];
  for (int i = 0; i < 16; ++i) W[i] = (const float*)d_in[4 + i];
  // enc: Wih0=W[0] Whh0=W[1] bih0=W[2] bhh0=W[3]  Wih1=W[4] Whh1=W[5] b=W[6],W[7]
  // dec: Wih0=W[8] Whh0=W[9] b=W[10],W[11]        Wih1=W[12] Whh1=W[13] b=W[14],W[15]

  char* ws = (char*)d_ws;
  size_t off = 0;
  auto alloc = [&](size_t bytes) {
    char* p = ws + off;
    off += (bytes + 255) & ~(size_t)255;
    return p;
  };
  unsigned* flags = (unsigned*)alloc(4 * 128 * sizeof(unsigned));
  float*    zeros = (float*)alloc((size_t)32 * 1024 * 4);
  __bf16*   Xe   = (__bf16*)alloc((size_t)4096 * 512 * 2);
  __bf16*   Xd   = (__bf16*)alloc((size_t)4096 * 512 * 2);
  __bf16*   XP1  = (__bf16*)alloc((size_t)4096 * 4096 * 2);
  __bf16*   XP2  = (__bf16*)alloc((size_t)4096 * 4096 * 2);
  __bf16*   hE0  = (__bf16*)alloc((size_t)128 * SLAB * 2);
  __bf16*   hE1  = (__bf16*)alloc((size_t)128 * SLAB * 2);
  __bf16*   hD0  = (__bf16*)alloc((size_t)128 * SLAB * 2);
  __bf16*   hD1  = (__bf16*)alloc((size_t)128 * SLAB * 2);
  float*    cE0  = (float*)alloc((size_t)32 * 1024 * 4);
  float*    cE1  = (float*)alloc((size_t)32 * 1024 * 4);
  float*    cd0  = (float*)alloc((size_t)32 * 1024 * 4);
  float*    cd1  = (float*)alloc((size_t)32 * 1024 * 4);

  hipFuncSetAttribute((const void*)rnn_pair,
                      hipFuncAttributeMaxDynamicSharedMemorySize, RNN_SMEM);

  init_ws<<<128, 256, 0, stream>>>(zeros, flags);
  gather_emb<<<8192, 128, 0, stream>>>(src, tgt, enc_emb, dec_emb, Xe, Xd);

  // layer-0 x-parts (K=512) for both encoder and decoder, up front
  gemm_xp<<<1024, 256, 0, stream>>>(Xe, W[0], W[2], W[3], XP1, 512);
  gemm_xp<<<1024, 256, 0, stream>>>(Xd, W[8], W[10], W[11], XP2, 512);

  // encoder epoch: L0 (blocks 0-127) + L1 skewed (blocks 128-255)
  RnnArgs e0{W[1], nullptr, nullptr, nullptr, XP1, nullptr, nullptr,
             (const __bf16*)zeros, zeros, hE0, cE0, nullptr, flags + 0};
  RnnArgs e1{W[5], W[4], W[6], W[7], nullptr, hE0, flags + 0,
             (const __bf16*)zeros, zeros, hE1, cE1, nullptr, flags + 128};
  rnn_pair<<<256, 256, RNN_SMEM, stream>>>(e0, e1);

  // decoder epoch: L0 init = encL0 finals, L1 init = encL1 finals -> d_out
  RnnArgs d0{W[9], nullptr, nullptr, nullptr, XP2, nullptr, nullptr,
             hE0 + (size_t)127 * SLAB, cE0, hD0, cd0, nullptr, flags + 256};
  RnnArgs d1{W[13], W[12], W[14], W[15], nullptr, hD0, flags + 256,
             hE1 + (size_t)127 * SLAB, cE1, hD1, cd1, (float*)d_out, flags + 384};
  rnn_pair<<<256, 256, RNN_SMEM, stream>>>(d0, d1);
}